// Round 1
// baseline (3113.535 us; speedup 1.0000x reference)
//
#include <hip/hip_runtime.h>
#include <math.h>

#define NT 30
#define TT 60
#define S  90
#define NN 48
#define SS (S*S)            // 8100
#define RSZ (NT*S*S)        // 243000
#define NEGF (-1000000000.0f)

// ---------------- workspace layout (floats) ----------------
// erule  : [0, RSZ)
// mchart : [RSZ, RSZ + NN*NN)
// evec   : [.., + NN*NN*S)
// rmax   : [.., +1)

__global__ void k_rmax(const float* __restrict__ rule, float* __restrict__ rmax) {
    __shared__ float red[256];
    float v = -INFINITY;
    for (int i = threadIdx.x; i < RSZ; i += 256) v = fmaxf(v, rule[i]);
    red[threadIdx.x] = v;
    __syncthreads();
    for (int s = 128; s > 0; s >>= 1) {
        if (threadIdx.x < s) red[threadIdx.x] = fmaxf(red[threadIdx.x], red[threadIdx.x + s]);
        __syncthreads();
    }
    if (threadIdx.x == 0) rmax[0] = red[0];
}

__global__ void k_erule(const float* __restrict__ rule, const float* __restrict__ rmax,
                        float* __restrict__ erule) {
    int i = blockIdx.x * 256 + threadIdx.x;
    if (i < RSZ) erule[i] = expf(rule[i] - rmax[0]);
}

__global__ void k_diag(const float* __restrict__ unary, float* __restrict__ mchart,
                       float* __restrict__ evec) {
    const int i = blockIdx.x;      // 48 blocks, 128 threads
    const int t = threadIdx.x;
    __shared__ float mxs;
    float v = (t < TT) ? unary[i * TT + t] : -INFINITY;
    if (t < 64) {
        for (int o = 32; o > 0; o >>= 1) v = fmaxf(v, __shfl_down(v, o));
        if (t == 0) mxs = v;
    }
    __syncthreads();
    float mx = mxs;
    if (t < S) {
        evec[(i * NN + i) * S + t] = (t < NT) ? 0.0f : expf(unary[i * TT + (t - NT)] - mx);
    }
    if (t == 0) mchart[i * NN + i] = mx;
}

__global__ __launch_bounds__(256) void k_level(int l,
                                               const float* __restrict__ erule,
                                               const float* __restrict__ rmax,
                                               float* __restrict__ mchart,
                                               float* __restrict__ evec) {
    const int s0  = blockIdx.x;     // span start
    const int j   = s0 + l;         // span end
    const int tid = threadIdx.x;
    const int lane = tid & 63;
    const int wid  = tid >> 6;

    __shared__ float el[S], er[S];
    __shared__ float wexp[64];
    __shared__ float alph[NT];
    __shared__ float part[NT * 4];
    __shared__ float Msh;

    // ---- scale M over splits, split weights ----
    float msum = -INFINITY;
    if (tid < l) msum = mchart[s0 * NN + (s0 + tid)] + mchart[(s0 + tid + 1) * NN + j];
    if (tid < 64) {
        float v = msum;
        for (int o = 32; o > 0; o >>= 1) v = fmaxf(v, __shfl_down(v, o));
        if (tid == 0) Msh = v;
    }
    __syncthreads();
    const float M = Msh;
    if (tid < l) wexp[tid] = expf(msum - M);

    // ---- G accumulation in registers: thread owns idx = tid + k*256 ----
    float Greg[32];
#pragma unroll
    for (int k = 0; k < 32; ++k) Greg[k] = 0.0f;

    __syncthreads();

    for (int m = 0; m < l; ++m) {
        if (tid < S)            el[tid]      = evec[(s0 * NN + (s0 + m)) * S + tid];
        else if (tid < 2 * S)   er[tid - S]  = evec[((s0 + m + 1) * NN + j) * S + (tid - S)];
        __syncthreads();
        const float w = wexp[m];
        int b = tid / S, c = tid % S;
        int idx = tid;
#pragma unroll
        for (int k = 0; k < 32; ++k) {
            if (idx < SS) Greg[k] += w * el[b] * er[c];
            idx += 256;
            c += 76; b += 2;
            if (c >= S) { c -= S; ++b; }
        }
        __syncthreads();
    }

    // ---- contraction acc[a] = <erule[a], G> ----
    const float Rm = rmax[0];
#pragma unroll 1
    for (int a = wid; a < NT; a += 4) {
        // each wave handles a subset of a's independently (wave-level reduce only)
        const float* __restrict__ ra = erule + a * SS;
        float p = 0.0f;
        int idx = tid;
#pragma unroll
        for (int k = 0; k < 32; ++k) {
            if (idx < SS) p += ra[idx] * Greg[k];
            idx += 256;
        }
        // reduce over this wave's 64 lanes; but partial sums live across ALL 256
        // threads, so store per-wave partial and finish after barrier.
        for (int o = 32; o > 0; o >>= 1) p += __shfl_down(p, o);
        if (lane == 0) part[a * 4 + wid] = p;
    }
    // NOTE: each wave computed partials only for its own a's. We need all 4 waves'
    // contributions per a. Redo properly: every wave must process every a.
    __syncthreads();
    // Correction pass: the loop above had wave w covering a = w, w+4, ... but its
    // partial only covers that wave's 64 threads' Greg slice. The other waves'
    // slices are missing. So instead recompute fully: all waves, all a.
    // (Cheap: 30*32 FMA per thread.)
#pragma unroll 1
    for (int a = 0; a < NT; ++a) {
        const float* __restrict__ ra = erule + a * SS;
        float p = 0.0f;
        int idx = tid;
#pragma unroll
        for (int k = 0; k < 32; ++k) {
            if (idx < SS) p += ra[idx] * Greg[k];
            idx += 256;
        }
        for (int o = 32; o > 0; o >>= 1) p += __shfl_down(p, o);
        if (lane == 0) part[a * 4 + wid] = p;
        __syncthreads();
        if (tid == 0) {
            float acc = part[a * 4 + 0] + part[a * 4 + 1] + part[a * 4 + 2] + part[a * 4 + 3];
            alph[a] = M + Rm + logf(acc);
        }
        __syncthreads();
    }

    // ---- renormalize cell ----
    {
        float v = (tid < NT) ? alph[tid] : -INFINITY;
        if (tid < 64) {
            for (int o = 32; o > 0; o >>= 1) v = fmaxf(v, __shfl_down(v, o));
            if (tid == 0) Msh = v;
        }
    }
    __syncthreads();
    const float mn = Msh;
    if (tid == 0) mchart[s0 * NN + j] = mn;
    if (tid < S) evec[(s0 * NN + j) * S + tid] = (tid < NT) ? expf(alph[tid] - mn) : 0.0f;
}

__global__ void k_final(const float* __restrict__ root, const float* __restrict__ mchart,
                        const float* __restrict__ evec, float* __restrict__ out) {
    const int t = threadIdx.x;  // 64 threads
    float v = 0.0f;
    if (t < NT) v = evec[(0 * NN + (NN - 1)) * S + t] * expf(root[t]);
    for (int o = 32; o > 0; o >>= 1) v += __shfl_down(v, o);
    if (t == 0) out[0] = mchart[NN - 1] + logf(v);
}

extern "C" void kernel_launch(void* const* d_in, const int* in_sizes, int n_in,
                              void* d_out, int out_size, void* d_ws, size_t ws_size,
                              hipStream_t stream) {
    const float* unary = (const float*)d_in[0];  // (48,60)
    const float* rule  = (const float*)d_in[1];  // (30,90,90)
    const float* root  = (const float*)d_in[2];  // (30,)
    float* out = (float*)d_out;

    float* ws     = (float*)d_ws;
    float* erule  = ws;
    float* mchart = ws + RSZ;
    float* evec   = mchart + NN * NN;
    float* rmax   = evec + NN * NN * S;

    k_rmax <<<1, 256, 0, stream>>>(rule, rmax);
    k_erule<<<(RSZ + 255) / 256, 256, 0, stream>>>(rule, rmax, erule);
    k_diag <<<NN, 128, 0, stream>>>(unary, mchart, evec);
    for (int l = 1; l < NN; ++l) {
        k_level<<<NN - l, 256, 0, stream>>>(l, erule, rmax, mchart, evec);
    }
    k_final<<<1, 64, 0, stream>>>(root, mchart, evec, out);
}

// Round 2
// 2495.828 us; speedup vs baseline: 1.2475x; 1.2475x over previous
//
#include <hip/hip_runtime.h>
#include <math.h>

#define NT 30
#define TT 60
#define S  90
#define NN 48
#define SS (S*S)            // 8100
#define RSZ (NT*SS)         // 243000
#define NEGF (-1.0e9f)
#define ABLK 4              // a-chunk blocks per span
#define ACH  8              // nonterminals per chunk (last has 6)

// ---------------- workspace layout (floats) ----------------
// erule : [0, RSZ)
// chart : [RSZ, RSZ + NN*NN*S)   raw log-alpha, 90 per cell
// rpart : [.., +128)
// rmax  : [.., +1)

__global__ void k_rmax1(const float* __restrict__ rule, float* __restrict__ rpart) {
    __shared__ float red[256];
    float v = -INFINITY;
    for (int i = blockIdx.x * 256 + threadIdx.x; i < RSZ; i += 256 * 128)
        v = fmaxf(v, rule[i]);
    red[threadIdx.x] = v;
    __syncthreads();
    for (int s = 128; s > 0; s >>= 1) {
        if (threadIdx.x < s) red[threadIdx.x] = fmaxf(red[threadIdx.x], red[threadIdx.x + s]);
        __syncthreads();
    }
    if (threadIdx.x == 0) rpart[blockIdx.x] = red[0];
}

__global__ void k_rmax2(const float* __restrict__ rpart, float* __restrict__ rmax) {
    const int t = threadIdx.x;  // 64
    float v = fmaxf(rpart[t], rpart[t + 64]);
    for (int o = 32; o > 0; o >>= 1) v = fmaxf(v, __shfl_down(v, o));
    if (t == 0) rmax[0] = v;
}

__global__ void k_erule(const float* __restrict__ rule, const float* __restrict__ rmax,
                        float* __restrict__ erule) {
    int i = blockIdx.x * 256 + threadIdx.x;
    if (i < RSZ) erule[i] = expf(rule[i] - rmax[0]);
}

__global__ void k_diag(const float* __restrict__ unary, float* __restrict__ chart) {
    const int i = blockIdx.x;      // 48 blocks, 128 threads
    const int t = threadIdx.x;
    if (t < S) chart[(i * NN + i) * S + t] = (t < NT) ? NEGF : unary[i * TT + (t - NT)];
}

__global__ __launch_bounds__(256) void k_level(int l,
                                               const float* __restrict__ erule,
                                               const float* __restrict__ rmax,
                                               float* __restrict__ chart) {
    const int s0  = blockIdx.x;          // span start
    const int j   = s0 + l;              // span end
    const int A0  = blockIdx.y * ACH;    // nonterminal chunk base
    const int tid = threadIdx.x;
    const int lane = tid & 63;
    const int wid  = tid >> 6;

    __shared__ float el[47 * S], er[47 * S];
    __shared__ float ml[47], mr[47], wexp[47];
    __shared__ float part[ACH * 4];
    __shared__ float Msh;

    // ---- bulk stage all 2*l rows (raw log values) ----
    const float* lbase = chart + (s0 * NN + s0) * S;   // left rows contiguous
    for (int i = tid; i < l * S; i += 256) el[i] = lbase[i];
    for (int i = tid; i < l * S; i += 256) {
        int r = i / S, c = i - r * S;
        er[i] = chart[((s0 + r + 1) * NN + j) * S + c];
    }
    // fill NT..S-1 slots of this cell with NEG (one y-block does it)
    if (blockIdx.y == 0 && tid >= NT && tid < S)
        chart[(s0 * NN + j) * S + tid] = NEGF;
    __syncthreads();

    // ---- per-row maxes (wave per row) ----
    for (int r = wid; r < 2 * l; r += 4) {
        const float* row = (r < l) ? (el + r * S) : (er + (r - l) * S);
        float v = row[lane];
        if (lane < S - 64) v = fmaxf(v, row[64 + lane]);
        for (int o = 32; o > 0; o >>= 1) v = fmaxf(v, __shfl_down(v, o));
        if (lane == 0) { if (r < l) ml[r] = v; else mr[r - l] = v; }
    }
    __syncthreads();

    // ---- split scale M, split weights (wave 0) ----
    if (wid == 0) {
        float msum = (lane < l) ? ml[lane] + mr[lane] : -INFINITY;
        float v = msum;
        for (int o = 32; o > 0; o >>= 1) v = fmaxf(v, __shfl_down(v, o));
        float M = __shfl(v, 0);
        if (lane == 0) Msh = M;
        if (lane < l) wexp[lane] = expf(msum - M);
    }
    __syncthreads();

    // ---- exponentiate rows in place; fold split weight into left rows ----
    for (int i = tid; i < l * S; i += 256) {
        int r = i / S;
        el[i] = expf(el[i] - ml[r]) * wexp[r];
        er[i] = expf(er[i] - mr[r]);
    }
    __syncthreads();

    // ---- G accumulation in registers (no barriers) ----
    float G[32];
#pragma unroll
    for (int k = 0; k < 32; ++k) G[k] = 0.f;
    {
        const int b00 = tid / S;
        const int c00 = tid - b00 * S;
        for (int m = 0; m < l; ++m) {
            const float* eb = el + m * S;
            const float* ec = er + m * S;
            int b = b00, c = c00;
#pragma unroll
            for (int k = 0; k < 32; ++k) {
                int idx = tid + (k << 8);
                if (idx < SS) G[k] += eb[b] * ec[c];
                c += 76; b += 2;
                if (c >= S) { c -= S; ++b; }
            }
        }
    }

    // ---- contraction: pa[a] = <erule[A0+a], G>, no barriers ----
    float pa[ACH];
#pragma unroll
    for (int a = 0; a < ACH; ++a) pa[a] = 0.f;
#pragma unroll 4
    for (int k = 0; k < 32; ++k) {
        int idx = tid + (k << 8);
        if (idx < SS) {
            float g = G[k];
#pragma unroll
            for (int a = 0; a < ACH; ++a) {
                if (A0 + a < NT) pa[a] += erule[(A0 + a) * SS + idx] * g;
            }
        }
    }
#pragma unroll
    for (int a = 0; a < ACH; ++a) {
        float p = pa[a];
        for (int o = 32; o > 0; o >>= 1) p += __shfl_down(p, o);
        if (lane == 0) part[a * 4 + wid] = p;
    }
    __syncthreads();

    // ---- finalize: 8 parallel logf, write raw log-alpha ----
    if (tid < ACH && A0 + tid < NT) {
        float acc = part[tid * 4] + part[tid * 4 + 1] + part[tid * 4 + 2] + part[tid * 4 + 3];
        chart[(s0 * NN + j) * S + A0 + tid] = Msh + rmax[0] + logf(acc);
    }
}

__global__ void k_final(const float* __restrict__ root, const float* __restrict__ chart,
                        float* __restrict__ out) {
    const int t = threadIdx.x;  // 64
    float v = (t < NT) ? chart[(0 * NN + (NN - 1)) * S + t] + root[t] : -INFINITY;
    float m = v;
    for (int o = 32; o > 0; o >>= 1) m = fmaxf(m, __shfl_down(m, o));
    m = __shfl(m, 0);
    float e = (t < NT) ? expf(v - m) : 0.f;
    for (int o = 32; o > 0; o >>= 1) e += __shfl_down(e, o);
    if (t == 0) out[0] = m + logf(e);
}

extern "C" void kernel_launch(void* const* d_in, const int* in_sizes, int n_in,
                              void* d_out, int out_size, void* d_ws, size_t ws_size,
                              hipStream_t stream) {
    const float* unary = (const float*)d_in[0];  // (48,60)
    const float* rule  = (const float*)d_in[1];  // (30,90,90)
    const float* root  = (const float*)d_in[2];  // (30,)
    float* out = (float*)d_out;

    float* ws    = (float*)d_ws;
    float* erule = ws;
    float* chart = ws + RSZ;
    float* rpart = chart + NN * NN * S;
    float* rmax  = rpart + 128;

    k_rmax1<<<128, 256, 0, stream>>>(rule, rpart);
    k_rmax2<<<1, 64, 0, stream>>>(rpart, rmax);
    k_erule<<<(RSZ + 255) / 256, 256, 0, stream>>>(rule, rmax, erule);
    k_diag <<<NN, 128, 0, stream>>>(unary, chart);
    for (int l = 1; l < NN; ++l) {
        k_level<<<dim3(NN - l, ABLK), 256, 0, stream>>>(l, erule, rmax, chart);
    }
    k_final<<<1, 64, 0, stream>>>(root, chart, out);
}

// Round 3
// 1551.308 us; speedup vs baseline: 2.0070x; 1.6089x over previous
//
#include <hip/hip_runtime.h>
#include <math.h>

#define NT 30
#define TT 60
#define S  90
#define NN 48
#define SS (S*S)            // 8100
#define RSZ (NT*SS)         // 243000
#define NEGF (-1.0e9f)

// ---------------- workspace layout (floats) ----------------
// erule : [0, RSZ)
// chart : [RSZ, RSZ + NN*NN*S)   raw log-alpha, 90 per cell
// rpart : [.., +128)
// rmax  : [.., +1)

__global__ void k_rmax1(const float* __restrict__ rule, float* __restrict__ rpart) {
    __shared__ float red[256];
    float v = -INFINITY;
    for (int i = blockIdx.x * 256 + threadIdx.x; i < RSZ; i += 256 * 128)
        v = fmaxf(v, rule[i]);
    red[threadIdx.x] = v;
    __syncthreads();
    for (int s = 128; s > 0; s >>= 1) {
        if (threadIdx.x < s) red[threadIdx.x] = fmaxf(red[threadIdx.x], red[threadIdx.x + s]);
        __syncthreads();
    }
    if (threadIdx.x == 0) rpart[blockIdx.x] = red[0];
}

__global__ void k_rmax2(const float* __restrict__ rpart, float* __restrict__ rmax) {
    const int t = threadIdx.x;  // 64
    float v = fmaxf(rpart[t], rpart[t + 64]);
    for (int o = 32; o > 0; o >>= 1) v = fmaxf(v, __shfl_down(v, o));
    if (t == 0) rmax[0] = v;
}

__global__ void k_erule(const float* __restrict__ rule, const float* __restrict__ rmax,
                        float* __restrict__ erule) {
    int i = blockIdx.x * 256 + threadIdx.x;
    if (i < RSZ) erule[i] = expf(rule[i] - rmax[0]);
}

__global__ void k_diag(const float* __restrict__ unary, float* __restrict__ chart) {
    const int i = blockIdx.x;      // 48 blocks, 128 threads
    const int t = threadIdx.x;
    if (t < S) chart[(i * NN + i) * S + t] = (t < NT) ? NEGF : unary[i * TT + (t - NT)];
}

// grid = (NN - l, NT); one block computes one (span, nonterminal) output.
__global__ __launch_bounds__(256) void k_level(int l,
                                               const float* __restrict__ erule,
                                               const float* __restrict__ rmax,
                                               float* __restrict__ chart) {
    const int s0  = blockIdx.x;          // span start
    const int j   = s0 + l;              // span end
    const int a   = blockIdx.y;          // nonterminal (0..29)
    const int tid = threadIdx.x;
    const int lane = tid & 63;
    const int wid  = tid >> 6;

    __shared__ float el[47 * S], er[47 * S];
    __shared__ float ml[47], mr[47], wexp[47];
    __shared__ float part[4];
    __shared__ float Msh;

    // ---- bulk stage all 2*l rows (raw log values) ----
    const float* lbase = chart + (s0 * NN + s0) * S;   // left rows contiguous
    for (int i = tid; i < l * S; i += 256) el[i] = lbase[i];
    for (int i = tid; i < l * S; i += 256) {
        int r = i / S, c = i - r * S;
        er[i] = chart[((s0 + r + 1) * NN + j) * S + c];
    }
    // fill terminal slots of this new cell with NEG (one y-block does it)
    if (a == 0 && tid >= NT && tid < S)
        chart[(s0 * NN + j) * S + tid] = NEGF;
    __syncthreads();

    // ---- per-row maxes (wave per row) ----
    for (int r = wid; r < 2 * l; r += 4) {
        const float* row = (r < l) ? (el + r * S) : (er + (r - l) * S);
        float v = row[lane];
        if (lane < S - 64) v = fmaxf(v, row[64 + lane]);
        for (int o = 32; o > 0; o >>= 1) v = fmaxf(v, __shfl_down(v, o));
        if (lane == 0) { if (r < l) ml[r] = v; else mr[r - l] = v; }
    }
    __syncthreads();

    // ---- split scale M, split weights (wave 0) ----
    if (wid == 0) {
        float msum = (lane < l) ? ml[lane] + mr[lane] : -INFINITY;
        float v = msum;
        for (int o = 32; o > 0; o >>= 1) v = fmaxf(v, __shfl_down(v, o));
        float M = __shfl(v, 0);
        if (lane == 0) Msh = M;
        if (lane < l) wexp[lane] = expf(msum - M);
    }
    __syncthreads();

    // ---- exponentiate rows in place; fold split weight into left rows ----
    for (int i = tid; i < l * S; i += 256) {
        int r = i / S;
        el[i] = expf(el[i] - ml[r]) * wexp[r];
        er[i] = expf(er[i] - mr[r]);
    }
    __syncthreads();

    // ---- G accumulation in registers (no barriers) ----
    // thread owns idx = tid + k*256
    float G[32];
#pragma unroll
    for (int k = 0; k < 32; ++k) G[k] = 0.f;
    {
        const int b00 = tid / S;
        const int c00 = tid - b00 * S;
        for (int m = 0; m < l; ++m) {
            const float* eb = el + m * S;
            const float* ec = er + m * S;
            int b = b00, c = c00;
#pragma unroll
            for (int k = 0; k < 32; ++k) {
                int idx = tid + (k << 8);
                if (idx < SS) G[k] += eb[b] * ec[c];
                c += 76; b += 2;
                if (c >= S) { c -= S; ++b; }
            }
        }
    }

    // ---- contraction: p = <erule[a], G>, fully unrolled coalesced loads ----
    const float* __restrict__ ra = erule + a * SS;
    float p = 0.f;
#pragma unroll
    for (int k = 0; k < 32; ++k) {
        int idx = tid + (k << 8);
        if (idx < SS) p += ra[idx] * G[k];
    }
    for (int o = 32; o > 0; o >>= 1) p += __shfl_down(p, o);
    if (lane == 0) part[wid] = p;
    __syncthreads();

    // ---- finalize: write raw log-alpha ----
    if (tid == 0) {
        float acc = part[0] + part[1] + part[2] + part[3];
        chart[(s0 * NN + j) * S + a] = Msh + rmax[0] + logf(acc);
    }
}

__global__ void k_final(const float* __restrict__ root, const float* __restrict__ chart,
                        float* __restrict__ out) {
    const int t = threadIdx.x;  // 64
    float v = (t < NT) ? chart[(0 * NN + (NN - 1)) * S + t] + root[t] : -INFINITY;
    float m = v;
    for (int o = 32; o > 0; o >>= 1) m = fmaxf(m, __shfl_down(m, o));
    m = __shfl(m, 0);
    float e = (t < NT) ? expf(v - m) : 0.f;
    for (int o = 32; o > 0; o >>= 1) e += __shfl_down(e, o);
    if (t == 0) out[0] = m + logf(e);
}

extern "C" void kernel_launch(void* const* d_in, const int* in_sizes, int n_in,
                              void* d_out, int out_size, void* d_ws, size_t ws_size,
                              hipStream_t stream) {
    const float* unary = (const float*)d_in[0];  // (48,60)
    const float* rule  = (const float*)d_in[1];  // (30,90,90)
    const float* root  = (const float*)d_in[2];  // (30,)
    float* out = (float*)d_out;

    float* ws    = (float*)d_ws;
    float* erule = ws;
    float* chart = ws + RSZ;
    float* rpart = chart + NN * NN * S;
    float* rmax  = rpart + 128;

    k_rmax1<<<128, 256, 0, stream>>>(rule, rpart);
    k_rmax2<<<1, 64, 0, stream>>>(rpart, rmax);
    k_erule<<<(RSZ + 255) / 256, 256, 0, stream>>>(rule, rmax, erule);
    k_diag <<<NN, 128, 0, stream>>>(unary, chart);
    for (int l = 1; l < NN; ++l) {
        k_level<<<dim3(NN - l, NT), 256, 0, stream>>>(l, erule, rmax, chart);
    }
    k_final<<<1, 64, 0, stream>>>(root, chart, out);
}

// Round 4
// 730.705 us; speedup vs baseline: 4.2610x; 2.1230x over previous
//
#include <hip/hip_runtime.h>
#include <math.h>

#define NT 30
#define TT 60
#define S  90
#define SP 92               // padded LDS row stride (16B-aligned rows)
#define NN 48
#define SS (S*S)            // 8100
#define RSZ (NT*SS)         // 243000
#define NEGF (-1.0e9f)

// ---------------- workspace layout (floats) ----------------
// erule : [0, RSZ+8)          (+8 pad, zeroed)
// chart : [RSZ+8, + NN*NN*S)  raw log-alpha, 90 per cell
// rpart : [.., +128)
// rmax  : [.., +1)

__global__ void k_rmax1(const float* __restrict__ rule, float* __restrict__ rpart) {
    __shared__ float red[256];
    float v = -INFINITY;
    for (int i = blockIdx.x * 256 + threadIdx.x; i < RSZ; i += 256 * 128)
        v = fmaxf(v, rule[i]);
    red[threadIdx.x] = v;
    __syncthreads();
    for (int s = 128; s > 0; s >>= 1) {
        if (threadIdx.x < s) red[threadIdx.x] = fmaxf(red[threadIdx.x], red[threadIdx.x + s]);
        __syncthreads();
    }
    if (threadIdx.x == 0) rpart[blockIdx.x] = red[0];
}

__global__ void k_rmax2(const float* __restrict__ rpart, float* __restrict__ rmax) {
    const int t = threadIdx.x;  // 64
    float v = fmaxf(rpart[t], rpart[t + 64]);
    for (int o = 32; o > 0; o >>= 1) v = fmaxf(v, __shfl_down(v, o));
    if (t == 0) rmax[0] = v;
}

__global__ void k_erule(const float* __restrict__ rule, const float* __restrict__ rmax,
                        float* __restrict__ erule) {
    int i = blockIdx.x * 256 + threadIdx.x;
    if (i < RSZ) erule[i] = expf(rule[i] - rmax[0]);
    if (blockIdx.x == 0 && threadIdx.x < 8) erule[RSZ + threadIdx.x] = 0.f;  // pad
}

__global__ void k_diag(const float* __restrict__ unary, float* __restrict__ chart) {
    const int i = blockIdx.x;      // 48 blocks, 128 threads
    const int t = threadIdx.x;
    if (t < S) chart[(i * NN + i) * S + t] = (t < NT) ? NEGF : unary[i * TT + (t - NT)];
}

// grid = (NN - l, NT); one block computes one (span, nonterminal) output.
__global__ __launch_bounds__(384, 1) void k_level(int l,
                                                  const float* __restrict__ erule,
                                                  const float* __restrict__ rmax,
                                                  float* __restrict__ chart) {
    const int s0  = blockIdx.x;          // span start
    const int j   = s0 + l;              // span end
    const int a   = blockIdx.y;          // nonterminal (0..29)
    const int tid = threadIdx.x;
    const int lane = tid & 63;
    const int wid  = tid >> 6;

    __shared__ float el[47 * SP + 8], er[47 * SP + 8];
    __shared__ float ml[47], mr[47], wexp[47];
    __shared__ float part[6];
    __shared__ float Msh;

    // ---- stage rows (float2); left rows are contiguous in chart ----
    const float* lbase = chart + (s0 * NN + s0) * S;
    for (int i2 = tid; i2 < l * (S / 2); i2 += 384) {
        int i = i2 * 2, r = i / S, c = i - r * S;
        float2 v = *(const float2*)(lbase + i);
        *(float2*)(&el[r * SP + c]) = v;
    }
    for (int i2 = tid; i2 < l * (S / 2); i2 += 384) {
        int i = i2 * 2, r = i / S, c = i - r * S;
        float2 v = *(const float2*)(chart + ((s0 + r + 1) * NN + j) * S + c);
        *(float2*)(&er[r * SP + c]) = v;
    }
    // zero pads (cols 90..91 of each used row, and 4 floats of row l)
    for (int r = tid; r < l; r += 384) {
        el[r * SP + 90] = 0.f; el[r * SP + 91] = 0.f;
        er[r * SP + 90] = 0.f; er[r * SP + 91] = 0.f;
    }
    if (tid < 4) er[l * SP + tid] = 0.f;
    // fill terminal slots of this new cell with NEG
    if (a == 0 && tid >= NT && tid < S)
        chart[(s0 * NN + j) * S + tid] = NEGF;
    __syncthreads();

    // ---- per-row maxes (wave per row, 6 waves) ----
    for (int r = wid; r < 2 * l; r += 6) {
        const float* row = (r < l) ? (el + r * SP) : (er + (r - l) * SP);
        float v = row[lane];
        if (lane < S - 64) v = fmaxf(v, row[64 + lane]);
        for (int o = 32; o > 0; o >>= 1) v = fmaxf(v, __shfl_down(v, o));
        if (lane == 0) { if (r < l) ml[r] = v; else mr[r - l] = v; }
    }
    __syncthreads();

    // ---- split scale M, split weights (wave 0) ----
    if (wid == 0) {
        float msum = (lane < l) ? ml[lane] + mr[lane] : -INFINITY;
        float v = msum;
        for (int o = 32; o > 0; o >>= 1) v = fmaxf(v, __shfl_down(v, o));
        float M = __shfl(v, 0);
        if (lane == 0) Msh = M;
        if (lane < l) wexp[lane] = expf(msum - M);
    }
    __syncthreads();

    // ---- exponentiate rows in place; fold split weight into left rows ----
    for (int i = tid; i < l * S; i += 384) {
        int r = i / S, c = i - r * S;
        el[r * SP + c] = expf(el[r * SP + c] - ml[r]) * wexp[r];
        er[r * SP + c] = expf(er[r * SP + c] - mr[r]);
    }
    __syncthreads();

    // ---- G accumulation: thread t<360 owns (b = t>>2, cols c0..c0+23) ----
    const bool act = tid < 360;
    const int  b   = tid >> 2;
    const int  q   = tid & 3;
    const int  c0  = q * 24;
    float G[24];
#pragma unroll
    for (int k = 0; k < 24; ++k) G[k] = 0.f;
    if (act) {
        for (int m = 0; m < l; ++m) {
            const float wb = el[m * SP + b];
            const float* ec = er + m * SP + c0;
            float vv[24];
            *(float4*)(vv +  0) = *(const float4*)(ec +  0);
            *(float4*)(vv +  4) = *(const float4*)(ec +  4);
            *(float4*)(vv +  8) = *(const float4*)(ec +  8);
            *(float4*)(vv + 12) = *(const float4*)(ec + 12);
            *(float4*)(vv + 16) = *(const float4*)(ec + 16);
            *(float4*)(vv + 20) = *(const float4*)(ec + 20);
#pragma unroll
            for (int k = 0; k < 24; ++k) {
                if (k < 18 || c0 + k < 90) G[k] += wb * vv[k];
            }
        }
    }

    // ---- contraction: p = <erule[a] strip, G> ----
    float p = 0.f;
    if (act) {
        const float* ra = erule + a * SS + b * S + c0;
        float vv[24];
#pragma unroll
        for (int k2 = 0; k2 < 12; ++k2)
            *(float2*)(vv + 2 * k2) = *(const float2*)(ra + 2 * k2);
#pragma unroll
        for (int k = 0; k < 24; ++k) {
            if (k < 18 || c0 + k < 90) p += vv[k] * G[k];
        }
    }
    for (int o = 32; o > 0; o >>= 1) p += __shfl_down(p, o);
    if (lane == 0) part[wid] = p;
    __syncthreads();

    // ---- finalize: write raw log-alpha ----
    if (tid == 0) {
        float acc = part[0] + part[1] + part[2] + part[3] + part[4] + part[5];
        chart[(s0 * NN + j) * S + a] = Msh + rmax[0] + logf(acc);
    }
}

__global__ void k_final(const float* __restrict__ root, const float* __restrict__ chart,
                        float* __restrict__ out) {
    const int t = threadIdx.x;  // 64
    float v = (t < NT) ? chart[(0 * NN + (NN - 1)) * S + t] + root[t] : -INFINITY;
    float m = v;
    for (int o = 32; o > 0; o >>= 1) m = fmaxf(m, __shfl_down(m, o));
    m = __shfl(m, 0);
    float e = (t < NT) ? expf(v - m) : 0.f;
    for (int o = 32; o > 0; o >>= 1) e += __shfl_down(e, o);
    if (t == 0) out[0] = m + logf(e);
}

extern "C" void kernel_launch(void* const* d_in, const int* in_sizes, int n_in,
                              void* d_out, int out_size, void* d_ws, size_t ws_size,
                              hipStream_t stream) {
    const float* unary = (const float*)d_in[0];  // (48,60)
    const float* rule  = (const float*)d_in[1];  // (30,90,90)
    const float* root  = (const float*)d_in[2];  // (30,)
    float* out = (float*)d_out;

    float* ws    = (float*)d_ws;
    float* erule = ws;
    float* chart = ws + RSZ + 8;
    float* rpart = chart + NN * NN * S;
    float* rmax  = rpart + 128;

    k_rmax1<<<128, 256, 0, stream>>>(rule, rpart);
    k_rmax2<<<1, 64, 0, stream>>>(rpart, rmax);
    k_erule<<<(RSZ + 255) / 256, 256, 0, stream>>>(rule, rmax, erule);
    k_diag <<<NN, 128, 0, stream>>>(unary, chart);
    for (int l = 1; l < NN; ++l) {
        k_level<<<dim3(NN - l, NT), 384, 0, stream>>>(l, erule, rmax, chart);
    }
    k_final<<<1, 64, 0, stream>>>(root, chart, out);
}

// Round 5
// 444.208 us; speedup vs baseline: 7.0092x; 1.6450x over previous
//
#include <hip/hip_runtime.h>
#include <math.h>

#define NT 30
#define TT 60
#define S  90
#define NN 48
#define SS (S*S)            // 8100
#define RSZ (NT*SS)         // 243000
#define NEGF (-1.0e9f)
#define PB 72               // bf16 LDS pitch (144B, 16B-aligned)

typedef __attribute__((ext_vector_type(8))) short bf16x8;
typedef __attribute__((ext_vector_type(4))) float f32x4;

__device__ __forceinline__ unsigned ordKey(float f) {
    unsigned u = __float_as_uint(f);
    return (u & 0x80000000u) ? ~u : (u | 0x80000000u);
}
__device__ __forceinline__ float decKey(unsigned k) {
    unsigned u = (k & 0x80000000u) ? (k ^ 0x80000000u) : ~k;
    return __uint_as_float(u);
}
__device__ __forceinline__ unsigned short f2bf(float f) {
    unsigned u = __float_as_uint(f);
    return (unsigned short)((u + 0x7fffu + ((u >> 16) & 1u)) >> 16);
}

__global__ void k_rmax1(const float* __restrict__ rule, float* __restrict__ rpart) {
    __shared__ float red[256];
    float v = -INFINITY;
    for (int i = blockIdx.x * 256 + threadIdx.x; i < RSZ; i += 256 * 128)
        v = fmaxf(v, rule[i]);
    red[threadIdx.x] = v;
    __syncthreads();
    for (int s = 128; s > 0; s >>= 1) {
        if (threadIdx.x < s) red[threadIdx.x] = fmaxf(red[threadIdx.x], red[threadIdx.x + s]);
        __syncthreads();
    }
    if (threadIdx.x == 0) rpart[blockIdx.x] = red[0];
}

__global__ void k_rmax2(const float* __restrict__ rpart, float* __restrict__ rmax) {
    const int t = threadIdx.x;  // 64
    float v = fmaxf(rpart[t], rpart[t + 64]);
    for (int o = 32; o > 0; o >>= 1) v = fmaxf(v, __shfl_down(v, o));
    if (t == 0) rmax[0] = v;
}

__global__ void k_erule(const float* __restrict__ rule, const float* __restrict__ rmax,
                        float* __restrict__ erule) {
    int i = blockIdx.x * 256 + threadIdx.x;
    if (i < RSZ) erule[i] = __expf(rule[i] - rmax[0]);
}

__global__ void k_init(unsigned* __restrict__ mkey) {
    for (int i = threadIdx.x; i < NN * NN; i += 256) mkey[i] = 0u;
}

__global__ void k_diag(const float* __restrict__ unary, float* __restrict__ chart,
                       unsigned* __restrict__ mkey) {
    const int i = blockIdx.x;      // 48 blocks, 128 threads
    const int t = threadIdx.x;
    if (t < 64) {
        float v = (t < TT) ? unary[i * TT + t] : -INFINITY;
        for (int o = 32; o > 0; o >>= 1) v = fmaxf(v, __shfl_down(v, o));
        if (t == 0) mkey[i * NN + i] = ordKey(v);
    }
    if (t < S) chart[(i * NN + i) * S + t] = (t < NT) ? NEGF : unary[i * TT + (t - NT)];
}

// grid = (NN - l, NT); one block computes one (span, nonterminal) output.
__global__ __launch_bounds__(384) void k_level(int l,
                                               const float* __restrict__ erule,
                                               const float* __restrict__ rmax,
                                               float* __restrict__ chart,
                                               unsigned* __restrict__ mkey) {
    const int s0  = blockIdx.x;          // span start
    const int j   = s0 + l;              // span end
    const int a   = blockIdx.y;          // nonterminal (0..29)
    const int tid = threadIdx.x;
    const int lane = tid & 63;
    const int w    = tid >> 6;           // wave id = tile row

    __shared__ unsigned short elT[96 * PB];   // [b][m] bf16, zero-padded
    __shared__ unsigned short erT[96 * PB];   // [c][m] bf16
    __shared__ float ml[47], mr[47], wexp[47];
    __shared__ float part[6];
    __shared__ float Msh;

    // ---- phase 0: zero frag arrays; terminal fill of new cell ----
    {
        uint4 z = {0u, 0u, 0u, 0u};
        uint4* z1 = (uint4*)elT;
        uint4* z2 = (uint4*)erT;
        for (int i = tid; i < (96 * PB * 2) / 16; i += 384) z1[i] = z;
        for (int i = tid; i < (96 * PB * 2) / 16; i += 384) z2[i] = z;
    }
    if (a == 0 && tid >= NT && tid < S)
        chart[(s0 * NN + j) * S + tid] = NEGF;

    // ---- phase 1: scales from per-cell max table (wave 0 only) ----
    if (w == 0) {
        float msum = -INFINITY;
        if (lane < l) {
            float a_ = decKey(mkey[s0 * NN + (s0 + lane)]);
            float b_ = decKey(mkey[(s0 + lane + 1) * NN + j]);
            ml[lane] = a_; mr[lane] = b_;
            msum = a_ + b_;
        }
        float v = msum;
        for (int o = 32; o > 0; o >>= 1) v = fmaxf(v, __shfl_down(v, o));
        float M = __shfl(v, 0);
        if (lane == 0) Msh = M;
        if (lane < l) wexp[lane] = __expf(msum - M);
    }
    __syncthreads();

    // ---- phase 2: exp + transpose + bf16 cast ----
    const float* lbase = chart + (s0 * NN + s0) * S;   // left rows contiguous
    for (int i = tid; i < l * S; i += 384) {
        int r = i / S, x = i - r * S;
        float vl = lbase[i];
        float vr = chart[((s0 + r + 1) * NN + j) * S + x];
        elT[x * PB + r] = f2bf(__expf(vl - ml[r]) * wexp[r]);
        erT[x * PB + r] = f2bf(__expf(vr - mr[r]));
    }
    __syncthreads();

    // ---- phase 3: G via MFMA, 6 waves x 6 tiles, K padded to 64 ----
    f32x4 acc[6];
    {
        f32x4 zz = {0.f, 0.f, 0.f, 0.f};
#pragma unroll
        for (int tc = 0; tc < 6; ++tc) acc[tc] = zz;
    }
    const int arow = w * 16 + (lane & 15);
    const int koff = (lane >> 4) * 8;
    const int ksteps = (l > 32) ? 2 : 1;
    for (int ks = 0; ks < ksteps; ++ks) {
        bf16x8 af = *(const bf16x8*)(elT + arow * PB + ks * 32 + koff);
#pragma unroll
        for (int tc = 0; tc < 6; ++tc) {
            bf16x8 bfr = *(const bf16x8*)(erT + (tc * 16 + (lane & 15)) * PB + ks * 32 + koff);
            acc[tc] = __builtin_amdgcn_mfma_f32_16x16x32_bf16(af, bfr, acc[tc], 0, 0, 0);
        }
    }

    // ---- phase 4: contraction p = <erule[a], G> straight from accumulators ----
    // C layout: col = lane&15 (c within tile), row = (lane>>4)*4+reg (b within tile)
    const float* __restrict__ ru = erule + a * SS;
    const int rb = w * 16 + ((lane >> 4) << 2);
    const int cb = lane & 15;
    float p = 0.f;
#pragma unroll
    for (int tc = 0; tc < 6; ++tc) {
        int c = tc * 16 + cb;
        if (c < S) {
#pragma unroll
            for (int reg = 0; reg < 4; ++reg) {
                int b = rb + reg;
                if (b < S) p += ru[b * S + c] * acc[tc][reg];
            }
        }
    }
    for (int o = 32; o > 0; o >>= 1) p += __shfl_down(p, o);
    if (lane == 0) part[w] = p;
    __syncthreads();

    // ---- finalize ----
    if (tid == 0) {
        float s = part[0] + part[1] + part[2] + part[3] + part[4] + part[5];
        float alpha = Msh + rmax[0] + logf(s);
        chart[(s0 * NN + j) * S + a] = alpha;
        atomicMax(&mkey[s0 * NN + j], ordKey(alpha));
    }
}

__global__ void k_final(const float* __restrict__ root, const float* __restrict__ chart,
                        float* __restrict__ out) {
    const int t = threadIdx.x;  // 64
    float v = (t < NT) ? chart[(0 * NN + (NN - 1)) * S + t] + root[t] : -INFINITY;
    float m = v;
    for (int o = 32; o > 0; o >>= 1) m = fmaxf(m, __shfl_down(m, o));
    m = __shfl(m, 0);
    float e = (t < NT) ? __expf(v - m) : 0.f;
    for (int o = 32; o > 0; o >>= 1) e += __shfl_down(e, o);
    if (t == 0) out[0] = m + logf(e);
}

extern "C" void kernel_launch(void* const* d_in, const int* in_sizes, int n_in,
                              void* d_out, int out_size, void* d_ws, size_t ws_size,
                              hipStream_t stream) {
    const float* unary = (const float*)d_in[0];  // (48,60)
    const float* rule  = (const float*)d_in[1];  // (30,90,90)
    const float* root  = (const float*)d_in[2];  // (30,)
    float* out = (float*)d_out;

    float*    ws    = (float*)d_ws;
    float*    erule = ws;
    float*    chart = ws + RSZ;
    unsigned* mkey  = (unsigned*)(chart + NN * NN * S);
    float*    rpart = (float*)(mkey + NN * NN);
    float*    rmax  = rpart + 128;

    k_rmax1<<<128, 256, 0, stream>>>(rule, rpart);
    k_rmax2<<<1, 64, 0, stream>>>(rpart, rmax);
    k_erule<<<(RSZ + 255) / 256, 256, 0, stream>>>(rule, rmax, erule);
    k_init <<<1, 256, 0, stream>>>(mkey);
    k_diag <<<NN, 128, 0, stream>>>(unary, chart, mkey);
    for (int l = 1; l < NN; ++l) {
        k_level<<<dim3(NN - l, NT), 384, 0, stream>>>(l, erule, rmax, chart, mkey);
    }
    k_final<<<1, 64, 0, stream>>>(root, chart, out);
}